// Round 3
// baseline (5950.651 us; speedup 1.0000x reference)
//
#include <hip/hip_runtime.h>
#include <hip/hip_bf16.h>

typedef __attribute__((ext_vector_type(8))) short   short8;
typedef __attribute__((ext_vector_type(4))) float   floatx4;
typedef __attribute__((ext_vector_type(4))) unsigned short ushort4v;

#define ICH 256

// ---------------- conversion kernels ----------------

// feats: [n][256][M] f32 -> [n][M][256] bf16 (LDS transpose)
__global__ __launch_bounds__(256)
void convert_feats(const float* __restrict__ in, __hip_bfloat16* __restrict__ out, int M) {
    __shared__ float t[64][65];
    const int p0 = blockIdx.x * 64, n = blockIdx.y;
    const int tid = threadIdx.x;
    const float* ib = in + (size_t)n * ICH * M;
    __hip_bfloat16* ob = out + (size_t)n * M * ICH;
    const int lo = tid & 63, hi = tid >> 6;
    for (int c0 = 0; c0 < ICH; c0 += 64) {
        #pragma unroll
        for (int r = 0; r < 16; ++r) {
            int ic = hi + 4 * r;
            t[ic][lo] = ib[(size_t)(c0 + ic) * M + p0 + lo];
        }
        __syncthreads();
        #pragma unroll
        for (int r = 0; r < 16; ++r) {
            int pp = hi + 4 * r;
            ob[(size_t)(p0 + pp) * ICH + c0 + lo] = __float2bfloat16(t[lo][pp]);
        }
        __syncthreads();
    }
}

// Fragment-major weight layout:
//   out index = ((((((icb*9+s)*nocw + ocw)*4 + j)*2 + kk)*64 + lane)*8 + e
//   maps to   w[oc = ocw*64 + j*16 + (lane&15)][ic = icb*64 + kk*32 + (lane>>4)*8 + e]
// so one wave's A-frag load for (j,kk) is a single coalesced 1KB global_load_dwordx4.

// mid weights: in [4][256][256][3][3] f32 -> per-layer fragment-major bf16 (nocw=4)
__global__ __launch_bounds__(256)
void convert_wmid(const float* __restrict__ in, __hip_bfloat16* __restrict__ out) {
    int idx = blockIdx.x * 256 + threadIdx.x;   // 4 * 2,359,296/4 total per head
    int e    = idx & 7;
    int lane = (idx >> 3) & 63;
    int kk   = (idx >> 9) & 1;
    int j    = (idx >> 10) & 3;
    int ocw  = (idx >> 12) & 3;
    int r    = idx >> 14;
    int s    = r % 9;
    int t2   = r / 9;
    int icb  = t2 & 3;
    int l    = t2 >> 2;
    int oc = ocw * 64 + j * 16 + (lane & 15);
    int ic = icb * 64 + kk * 32 + (lane >> 4) * 8 + e;
    out[idx] = __float2bfloat16(in[(size_t)((l * 256 + oc) * 256 + ic) * 9 + s]);
}

// final weights: in [OC][256][3][3] f32 -> fragment-major bf16, oc zero-padded to nocw*64
__global__ __launch_bounds__(256)
void convert_wfin(const float* __restrict__ in, __hip_bfloat16* __restrict__ out,
                  int OC, int nocw) {
    int idx = blockIdx.x * 256 + threadIdx.x;   // 4*9*nocw*4*2*512 total
    int e    = idx & 7;
    int lane = (idx >> 3) & 63;
    int kk   = (idx >> 9) & 1;
    int j    = (idx >> 10) & 3;
    int r    = idx >> 12;
    int ocw  = r % nocw;
    int r2   = r / nocw;
    int s    = r2 % 9;
    int icb  = r2 / 9;
    int oc = ocw * 64 + j * 16 + (lane & 15);
    int ic = icb * 64 + kk * 32 + (lane >> 4) * 8 + e;
    float v = 0.0f;
    if (oc < OC) v = in[(size_t)(oc * 256 + ic) * 9 + s];
    out[idx] = __float2bfloat16(v);
}

// ---------------- MFMA conv kernel ----------------
// actin : bf16 [n][M][256] (ic contiguous)
// wfrag : fragment-major bf16 (see above)
// LDS: activation halo tile only, XOR-swizzled (chunk' = chunk ^ (row&7)).
template<int BW, bool FINAL, int KOUT>
__global__ __launch_bounds__(256, 3)
void conv_mfma(const __hip_bfloat16* __restrict__ actin,
               const __hip_bfloat16* __restrict__ wfrag,
               const float* __restrict__ bias,
               __hip_bfloat16* __restrict__ actout,
               float* __restrict__ fout,
               int H, int W, int nbX, int nocw, int OC,
               int anchor_off, int atot)
{
    constexpr int BH   = 128 / BW;
    constexpr int BWP  = BW + 2;
    constexpr int BHP  = BH + 2;
    constexpr int HTOT = BWP * BHP;   // 180 for both configs

    __shared__ short lds_act[HTOT * 64];

    const int M  = H * W;
    const int n  = blockIdx.z;
    const int by = blockIdx.x / nbX;
    const int bx = blockIdx.x - by * nbX;
    const int y0 = by * BH, x0 = bx * BW;
    const int tid  = threadIdx.x;
    const int lane = tid & 63, wv = tid >> 6;
    const int mw = wv >> 1, nw = wv & 1;
    const int ln = lane & 15, q = lane >> 4;
    const int sub = tid & 7, grp = tid >> 3;

    const short* actg = (const short*)actin + (size_t)n * M * ICH;
    const int ocw = blockIdx.y * 2 + mw;

    // B-frag logical base rows (halo coords, centered)
    int brow[4];
    #pragma unroll
    for (int i = 0; i < 4; ++i) {
        int t = nw * 64 + 16 * i + ln;
        brow[i] = (t / BW + 1) * BWP + (t % BW + 1);
    }

    floatx4 acc[4][4] = {};

    for (int icb = 0; icb < 4; ++icb) {
        // stage activation halo tile (HTOT px x 64 ic), swizzled
        #pragma unroll
        for (int it = 0; it < 6; ++it) {
            int hp = grp + 32 * it;
            if (hp < HTOT) {
                int hy = hp / BWP, hx = hp - hy * BWP;
                int gy = y0 - 1 + hy, gx = x0 - 1 + hx;
                short8 v = {};
                if ((unsigned)gy < (unsigned)H && (unsigned)gx < (unsigned)W)
                    v = *(const short8*)(actg + ((size_t)(gy * W + gx)) * ICH
                                         + icb * 64 + sub * 8);
                *(short8*)(&lds_act[hp * 64 + ((sub ^ (hp & 7)) * 8)]) = v;
            }
        }
        __syncthreads();

        const short* wicb = (const short*)wfrag
                          + ((size_t)icb * 9 * nocw) * 4096 + (size_t)lane * 8;
        #pragma unroll
        for (int s = 0; s < 9; ++s) {
            const short* wp = wicb + ((size_t)(s * nocw + ocw)) * 4096;
            short8 wv8[8];
            #pragma unroll
            for (int u = 0; u < 8; ++u)
                wv8[u] = *(const short8*)(wp + u * 512);

            const int dy = s / 3 - 1, dx = s % 3 - 1;
            const int soff = dy * BWP + dx;
            #pragma unroll
            for (int kk = 0; kk < 2; ++kk) {
                short8 bf[4];
                #pragma unroll
                for (int i = 0; i < 4; ++i) {
                    int row = brow[i] + soff;
                    bf[i] = *(const short8*)(
                        &lds_act[row * 64 + (((q + 4 * kk) ^ (row & 7)) * 8)]);
                }
                #pragma unroll
                for (int j = 0; j < 4; ++j)
                    #pragma unroll
                    for (int i = 0; i < 4; ++i)
                        acc[j][i] = __builtin_amdgcn_mfma_f32_16x16x32_bf16(
                            wv8[2 * j + kk], bf[i], acc[j][i], 0, 0, 0);
            }
        }
        __syncthreads();
    }

    // ---------------- epilogue ----------------
    const int oc0 = blockIdx.y * 128;
    if constexpr (!FINAL) {
        __hip_bfloat16* ob = actout + (size_t)n * M * ICH;
        #pragma unroll
        for (int j = 0; j < 4; ++j) {
            int oc = oc0 + mw * 64 + 16 * j + q * 4;
            float bv[4];
            #pragma unroll
            for (int r = 0; r < 4; ++r) bv[r] = bias[oc + r];
            #pragma unroll
            for (int i = 0; i < 4; ++i) {
                int t  = nw * 64 + 16 * i + ln;
                int ty = t / BW, tx = t % BW;
                int gy = y0 + ty;
                if (gy < H) {
                    union { ushort4v v; __hip_bfloat16 h[4]; } u;
                    #pragma unroll
                    for (int r = 0; r < 4; ++r)
                        u.h[r] = __float2bfloat16(fmaxf(acc[j][i][r] + bv[r], 0.0f));
                    *(ushort4v*)(ob + (size_t)(gy * W + x0 + tx) * ICH + oc) = u.v;
                }
            }
        }
    } else {
        float* fb = fout + (size_t)n * atot * KOUT;
        #pragma unroll
        for (int j = 0; j < 4; ++j) {
            int ocb = oc0 + mw * 64 + 16 * j + q * 4;
            #pragma unroll
            for (int i = 0; i < 4; ++i) {
                int t  = nw * 64 + 16 * i + ln;
                int ty = t / BW, tx = t % BW;
                int gy = y0 + ty;
                if (gy < H) {
                    int p = gy * W + x0 + tx;
                    #pragma unroll
                    for (int r = 0; r < 4; ++r) {
                        int oc = ocb + r;
                        if (oc < OC) {
                            int a = oc / KOUT, c = oc - a * KOUT;
                            fb[(size_t)(anchor_off + p * 9 + a) * KOUT + c] =
                                acc[j][i][r] + bias[oc];
                        }
                    }
                }
            }
        }
    }
}

// ---------------- host ----------------

extern "C" void kernel_launch(void* const* d_in, const int* in_sizes, int n_in,
                              void* d_out, int out_size, void* d_ws, size_t ws_size,
                              hipStream_t stream) {
    const float* feats[5];
    for (int i = 0; i < 5; i++) feats[i] = (const float*)d_in[i];
    const float* cls_conv_w = (const float*)d_in[5];
    const float* cls_conv_b = (const float*)d_in[6];
    const float* cls_out_w  = (const float*)d_in[7];
    const float* cls_out_b  = (const float*)d_in[8];
    const float* reg_conv_w = (const float*)d_in[9];
    const float* reg_conv_b = (const float*)d_in[10];
    const float* reg_out_w  = (const float*)d_in[11];
    const float* reg_out_b  = (const float*)d_in[12];

    // workspace layout (~64.5 MB; round-2 verified OK)
    char* wp = (char*)d_ws;
    __hip_bfloat16* featC = (__hip_bfloat16*)wp; wp += (size_t)2 * 16384 * 256 * 2;
    __hip_bfloat16* actA  = (__hip_bfloat16*)wp; wp += (size_t)2 * 16384 * 256 * 2;
    __hip_bfloat16* actB  = (__hip_bfloat16*)wp; wp += (size_t)2 * 16384 * 256 * 2;
    __hip_bfloat16* wmid[2];
    wmid[0] = (__hip_bfloat16*)wp; wp += (size_t)4 * 9 * 256 * 256 * 2;
    wmid[1] = (__hip_bfloat16*)wp; wp += (size_t)4 * 9 * 256 * 256 * 2;
    __hip_bfloat16* wfc = (__hip_bfloat16*)wp; wp += (size_t)9 * 896 * 256 * 2;
    __hip_bfloat16* wfr = (__hip_bfloat16*)wp; wp += (size_t)9 * 128 * 256 * 2;

    // one-time weight conversions (fragment-major)
    convert_wmid<<<4 * 9 * 256, 256, 0, stream>>>(cls_conv_w, wmid[0]);
    convert_wmid<<<4 * 9 * 256, 256, 0, stream>>>(reg_conv_w, wmid[1]);
    convert_wfin<<<(4 * 9 * 14 * 4 * 2 * 512) / 256, 256, 0, stream>>>(cls_out_w, wfc, 819, 14);
    convert_wfin<<<(4 * 9 * 2  * 4 * 2 * 512) / 256, 256, 0, stream>>>(reg_out_w, wfr, 36, 2);

    const int sizes[5] = {128, 64, 32, 16, 8};
    const int ATOT = 196416;   // sum(H*W)*9

    float* cls_out = (float*)d_out;
    float* reg_out = (float*)d_out + (size_t)2 * ATOT * 91;
    const float* convb[2] = { cls_conv_b, reg_conv_b };

    int aoff = 0;
    for (int sc = 0; sc < 5; ++sc) {
        const int Hs = sizes[sc], Ws = sizes[sc], M = Hs * Ws;
        const int BWv = (Ws >= 16) ? 16 : 8;
        const int BHv = 128 / BWv;
        const int nbX = (Ws + BWv - 1) / BWv;
        const int nbY = (Hs + BHv - 1) / BHv;
        dim3 gmid(nbX * nbY, 2, 2);

        convert_feats<<<dim3(M / 64, 2), 256, 0, stream>>>(feats[sc], featC, M);

        for (int h = 0; h < 2; ++h) {
            const __hip_bfloat16* src = featC;
            __hip_bfloat16* dst = actA;
            for (int l = 0; l < 4; ++l) {
                const __hip_bfloat16* wl = wmid[h] + (size_t)l * 9 * 256 * 256;
                const float* bl = convb[h] + l * 256;
                if (BWv == 16)
                    conv_mfma<16, false, 1><<<gmid, 256, 0, stream>>>(
                        src, wl, bl, dst, nullptr, Hs, Ws, nbX, 4, 256, 0, 0);
                else
                    conv_mfma<8, false, 1><<<gmid, 256, 0, stream>>>(
                        src, wl, bl, dst, nullptr, Hs, Ws, nbX, 4, 256, 0, 0);
                src = dst;
                dst = (dst == actA) ? actB : actA;
            }
            if (h == 0) {
                dim3 gf(nbX * nbY, 7, 2);   // 896/128
                if (BWv == 16)
                    conv_mfma<16, true, 91><<<gf, 256, 0, stream>>>(
                        src, wfc, cls_out_b, nullptr, cls_out, Hs, Ws, nbX, 14, 819, aoff, ATOT);
                else
                    conv_mfma<8, true, 91><<<gf, 256, 0, stream>>>(
                        src, wfc, cls_out_b, nullptr, cls_out, Hs, Ws, nbX, 14, 819, aoff, ATOT);
            } else {
                dim3 gf(nbX * nbY, 1, 2);   // 128/128
                if (BWv == 16)
                    conv_mfma<16, true, 4><<<gf, 256, 0, stream>>>(
                        src, wfr, reg_out_b, nullptr, reg_out, Hs, Ws, nbX, 2, 36, aoff, ATOT);
                else
                    conv_mfma<8, true, 4><<<gf, 256, 0, stream>>>(
                        src, wfr, reg_out_b, nullptr, reg_out, Hs, Ws, nbX, 2, 36, aoff, ATOT);
            }
        }
        aoff += M * 9;
    }
}

// Round 4
// 3147.957 us; speedup vs baseline: 1.8903x; 1.8903x over previous
//
#include <hip/hip_runtime.h>
#include <hip/hip_bf16.h>

typedef __attribute__((ext_vector_type(8))) short   short8;
typedef __attribute__((ext_vector_type(4))) float   floatx4;
typedef __attribute__((ext_vector_type(4))) unsigned short ushort4v;

#define ICH 256

// ---------------- conversion kernels ----------------

// feats: [n][256][M] f32 -> [n][M][256] bf16 (LDS transpose)
__global__ __launch_bounds__(256)
void convert_feats(const float* __restrict__ in, __hip_bfloat16* __restrict__ out, int M) {
    __shared__ float t[64][65];
    const int p0 = blockIdx.x * 64, n = blockIdx.y;
    const int tid = threadIdx.x;
    const float* ib = in + (size_t)n * ICH * M;
    __hip_bfloat16* ob = out + (size_t)n * M * ICH;
    const int lo = tid & 63, hi = tid >> 6;
    for (int c0 = 0; c0 < ICH; c0 += 64) {
        #pragma unroll
        for (int r = 0; r < 16; ++r) {
            int ic = hi + 4 * r;
            t[ic][lo] = ib[(size_t)(c0 + ic) * M + p0 + lo];
        }
        __syncthreads();
        #pragma unroll
        for (int r = 0; r < 16; ++r) {
            int pp = hi + 4 * r;
            ob[(size_t)(p0 + pp) * ICH + c0 + lo] = __float2bfloat16(t[lo][pp]);
        }
        __syncthreads();
    }
}

// Fragment-major weight layout:
//   idx = ((g*nocw + ocw)*8 + j*2 + kk)*512 + lane*8 + e,  g = icb*9+s
//   maps to w[oc = ocw*64 + j*16 + (lane&15)][ic = icb*64 + kk*32 + (lane>>4)*8 + e]

// mid weights: in [4][256][256][3][3] f32 -> per-layer fragment-major bf16 (nocw=4)
__global__ __launch_bounds__(256)
void convert_wmid(const float* __restrict__ in, __hip_bfloat16* __restrict__ out) {
    int idx = blockIdx.x * 256 + threadIdx.x;
    int e    = idx & 7;
    int lane = (idx >> 3) & 63;
    int kk   = (idx >> 9) & 1;
    int j    = (idx >> 10) & 3;
    int ocw  = (idx >> 12) & 3;
    int r    = idx >> 14;
    int s    = r % 9;
    int t2   = r / 9;
    int icb  = t2 & 3;
    int l    = t2 >> 2;
    int oc = ocw * 64 + j * 16 + (lane & 15);
    int ic = icb * 64 + kk * 32 + (lane >> 4) * 8 + e;
    out[idx] = __float2bfloat16(in[(size_t)((l * 256 + oc) * 256 + ic) * 9 + s]);
}

// final weights: in [OC][256][3][3] f32 -> fragment-major bf16, oc zero-padded to nocw*64
__global__ __launch_bounds__(256)
void convert_wfin(const float* __restrict__ in, __hip_bfloat16* __restrict__ out,
                  int OC, int nocw) {
    int idx = blockIdx.x * 256 + threadIdx.x;
    int e    = idx & 7;
    int lane = (idx >> 3) & 63;
    int kk   = (idx >> 9) & 1;
    int j    = (idx >> 10) & 3;
    int r    = idx >> 12;
    int ocw  = r % nocw;
    int r2   = r / nocw;
    int s    = r2 % 9;
    int icb  = r2 / 9;
    int oc = ocw * 64 + j * 16 + (lane & 15);
    int ic = icb * 64 + kk * 32 + (lane >> 4) * 8 + e;
    float v = 0.0f;
    if (oc < OC) v = in[(size_t)(oc * 256 + ic) * 9 + s];
    out[idx] = __float2bfloat16(v);
}

// ---------------- MFMA conv kernel ----------------
template<int BW, bool FINAL, int KOUT>
__global__ __launch_bounds__(256, 2)
void conv_mfma(const __hip_bfloat16* __restrict__ actin,
               const __hip_bfloat16* __restrict__ wfrag,
               const float* __restrict__ bias,
               __hip_bfloat16* __restrict__ actout,
               float* __restrict__ fout,
               int H, int W, int nbX, int nocw, int OC,
               int anchor_off, int atot)
{
    constexpr int BH   = 128 / BW;
    constexpr int BWP  = BW + 2;
    constexpr int BHP  = BH + 2;
    constexpr int HTOT = BWP * BHP;   // 180

    __shared__ __align__(16) short lds_act[HTOT * 64];

    const int M  = H * W;
    const int n  = blockIdx.z;
    const int by = blockIdx.x / nbX;
    const int bx = blockIdx.x - by * nbX;
    const int y0 = by * BH, x0 = bx * BW;
    const int tid  = threadIdx.x;
    const int lane = tid & 63, wv = tid >> 6;
    const int mw = wv >> 1, nw = wv & 1;
    const int ln = lane & 15, q = lane >> 4;
    const int sub = tid & 7, grp = tid >> 3;

    const short* actg = (const short*)actin + (size_t)n * M * ICH;
    const int ocw = blockIdx.y * 2 + mw;
    const short* wbase = (const short*)wfrag + (size_t)ocw * 4096 + (size_t)lane * 8;

    int brow[4];
    #pragma unroll
    for (int i = 0; i < 4; ++i) {
        int t = nw * 64 + 16 * i + ln;
        brow[i] = (t / BW + 1) * BWP + (t % BW + 1);
    }

    floatx4 acc[4][4] = {};
    short8 wb0[8], wb1[8];

    auto loadw = [&](short8* dst, int g) {
        const short* wp = wbase + (size_t)g * nocw * 4096;
        #pragma unroll
        for (int u = 0; u < 8; ++u)
            dst[u] = *(const short8*)(wp + u * 512);
    };

    loadw(wb0, 0);

    for (int icb2 = 0; icb2 < 2; ++icb2) {
        #pragma unroll
        for (int hh = 0; hh < 2; ++hh) {
            const int icb = icb2 * 2 + hh;
            // stage activation halo tile (HTOT px x 64 ic), XOR-swizzled
            #pragma unroll
            for (int it = 0; it < 6; ++it) {
                int hp = grp + 32 * it;
                if (hp < HTOT) {
                    int hy = hp / BWP, hx = hp - hy * BWP;
                    int gy = y0 - 1 + hy, gx = x0 - 1 + hx;
                    short8 v = {};
                    if ((unsigned)gy < (unsigned)H && (unsigned)gx < (unsigned)W)
                        v = *(const short8*)(actg + (size_t)(gy * W + gx) * ICH
                                             + icb * 64 + sub * 8);
                    *(short8*)(&lds_act[hp * 64 + ((sub ^ (hp & 7)) * 8)]) = v;
                }
            }
            __syncthreads();

            #pragma unroll
            for (int sl = 0; sl < 9; ++sl) {
                const int local = hh * 9 + sl;           // compile-time after unroll
                const int g = icb2 * 18 + local;
                short8* curw = (local & 1) ? wb1 : wb0;  // folds to direct ref
                short8* nxtw = (local & 1) ? wb0 : wb1;
                if (g < 35) loadw(nxtw, g + 1);          // prefetch next tap

                const int dy = sl / 3 - 1, dx = sl % 3 - 1;
                const int soff = dy * BWP + dx;
                #pragma unroll
                for (int kk = 0; kk < 2; ++kk) {
                    short8 bf[4];
                    #pragma unroll
                    for (int i = 0; i < 4; ++i) {
                        int row = brow[i] + soff;
                        bf[i] = *(const short8*)(
                            &lds_act[row * 64 + (((q + 4 * kk) ^ (row & 7)) * 8)]);
                    }
                    #pragma unroll
                    for (int j = 0; j < 4; ++j)
                        #pragma unroll
                        for (int i = 0; i < 4; ++i)
                            acc[j][i] = __builtin_amdgcn_mfma_f32_16x16x32_bf16(
                                curw[2 * j + kk], bf[i], acc[j][i], 0, 0, 0);
                }
            }
            __syncthreads();
        }
    }

    // ---------------- epilogue ----------------
    const int oc0 = blockIdx.y * 128;
    if constexpr (!FINAL) {
        __hip_bfloat16* ob = actout + (size_t)n * M * ICH;
        #pragma unroll
        for (int j = 0; j < 4; ++j) {
            int oc = oc0 + mw * 64 + 16 * j + q * 4;
            float bv[4];
            #pragma unroll
            for (int r = 0; r < 4; ++r) bv[r] = bias[oc + r];
            #pragma unroll
            for (int i = 0; i < 4; ++i) {
                int t  = nw * 64 + 16 * i + ln;
                int ty = t / BW, tx = t % BW;
                int gy = y0 + ty;
                if (gy < H) {
                    union { ushort4v v; __hip_bfloat16 h[4]; } u;
                    #pragma unroll
                    for (int r = 0; r < 4; ++r)
                        u.h[r] = __float2bfloat16(fmaxf(acc[j][i][r] + bv[r], 0.0f));
                    *(ushort4v*)(ob + (size_t)(gy * W + x0 + tx) * ICH + oc) = u.v;
                }
            }
        }
    } else {
        // LDS-staged permuted store: global idx = aoff*K + p*9K + oc  (oc-contiguous)
        float* lds_f = (float*)lds_act;        // reuse; 32 px x 129 floats = 16.5 KB
        const int NOC = 9 * KOUT;
        const int ocn = (NOC - oc0 < 128) ? (NOC - oc0) : 128;
        float* fb = fout + (size_t)n * atot * KOUT + (size_t)anchor_off * KOUT;
        #pragma unroll
        for (int c = 0; c < 4; ++c) {
            if (nw == (c >> 1)) {
                #pragma unroll
                for (int ii = 0; ii < 2; ++ii) {
                    const int i  = 2 * (c & 1) + ii;
                    const int px = 16 * ii + ln;
                    #pragma unroll
                    for (int j = 0; j < 4; ++j) {
                        #pragma unroll
                        for (int r = 0; r < 4; ++r) {
                            int ocl = mw * 64 + 16 * j + q * 4 + r;
                            int oc  = oc0 + ocl;
                            float bv = (oc < OC) ? bias[oc] : 0.0f;
                            lds_f[px * 129 + ocl] = acc[j][i][r] + bv;
                        }
                    }
                }
            }
            __syncthreads();
            #pragma unroll
            for (int pp = 0; pp < 8; ++pp) {
                int px = wv * 8 + pp;
                int t  = c * 32 + px;
                int ty = t / BW, tx = t - ty * BW;
                int gy = y0 + ty;
                if (gy < H) {
                    size_t base = (size_t)(gy * W + x0 + tx) * NOC + oc0;
                    #pragma unroll
                    for (int u = 0; u < 2; ++u) {
                        int oc = lane + 64 * u;
                        if (oc < ocn) fb[base + oc] = lds_f[px * 129 + oc];
                    }
                }
            }
            __syncthreads();
        }
    }
}

// ---------------- host ----------------

extern "C" void kernel_launch(void* const* d_in, const int* in_sizes, int n_in,
                              void* d_out, int out_size, void* d_ws, size_t ws_size,
                              hipStream_t stream) {
    const float* feats[5];
    for (int i = 0; i < 5; i++) feats[i] = (const float*)d_in[i];
    const float* cls_conv_w = (const float*)d_in[5];
    const float* cls_conv_b = (const float*)d_in[6];
    const float* cls_out_w  = (const float*)d_in[7];
    const float* cls_out_b  = (const float*)d_in[8];
    const float* reg_conv_w = (const float*)d_in[9];
    const float* reg_conv_b = (const float*)d_in[10];
    const float* reg_out_w  = (const float*)d_in[11];
    const float* reg_out_b  = (const float*)d_in[12];

    char* wp = (char*)d_ws;
    __hip_bfloat16* featC = (__hip_bfloat16*)wp; wp += (size_t)2 * 16384 * 256 * 2;
    __hip_bfloat16* actA  = (__hip_bfloat16*)wp; wp += (size_t)2 * 16384 * 256 * 2;
    __hip_bfloat16* actB  = (__hip_bfloat16*)wp; wp += (size_t)2 * 16384 * 256 * 2;
    __hip_bfloat16* wmid[2];
    wmid[0] = (__hip_bfloat16*)wp; wp += (size_t)4 * 9 * 256 * 256 * 2;
    wmid[1] = (__hip_bfloat16*)wp; wp += (size_t)4 * 9 * 256 * 256 * 2;
    __hip_bfloat16* wfc = (__hip_bfloat16*)wp; wp += (size_t)9 * 896 * 256 * 2;
    __hip_bfloat16* wfr = (__hip_bfloat16*)wp; wp += (size_t)9 * 128 * 256 * 2;

    convert_wmid<<<4 * 9 * 256, 256, 0, stream>>>(cls_conv_w, wmid[0]);
    convert_wmid<<<4 * 9 * 256, 256, 0, stream>>>(reg_conv_w, wmid[1]);
    convert_wfin<<<(4 * 9 * 14 * 4 * 2 * 512) / 256, 256, 0, stream>>>(cls_out_w, wfc, 819, 14);
    convert_wfin<<<(4 * 9 * 2  * 4 * 2 * 512) / 256, 256, 0, stream>>>(reg_out_w, wfr, 36, 2);

    const int sizes[5] = {128, 64, 32, 16, 8};
    const int ATOT = 196416;

    float* cls_out = (float*)d_out;
    float* reg_out = (float*)d_out + (size_t)2 * ATOT * 91;
    const float* convb[2] = { cls_conv_b, reg_conv_b };

    int aoff = 0;
    for (int sc = 0; sc < 5; ++sc) {
        const int Hs = sizes[sc], Ws = sizes[sc], M = Hs * Ws;
        const int BWv = (Ws >= 16) ? 16 : 8;
        const int BHv = 128 / BWv;
        const int nbX = (Ws + BWv - 1) / BWv;
        const int nbY = (Hs + BHv - 1) / BHv;
        dim3 gmid(nbX * nbY, 2, 2);

        convert_feats<<<dim3(M / 64, 2), 256, 0, stream>>>(feats[sc], featC, M);

        for (int h = 0; h < 2; ++h) {
            const __hip_bfloat16* src = featC;
            __hip_bfloat16* dst = actA;
            for (int l = 0; l < 4; ++l) {
                const __hip_bfloat16* wl = wmid[h] + (size_t)l * 9 * 256 * 256;
                const float* bl = convb[h] + l * 256;
                if (BWv == 16)
                    conv_mfma<16, false, 1><<<gmid, 256, 0, stream>>>(
                        src, wl, bl, dst, nullptr, Hs, Ws, nbX, 4, 256, 0, 0);
                else
                    conv_mfma<8, false, 1><<<gmid, 256, 0, stream>>>(
                        src, wl, bl, dst, nullptr, Hs, Ws, nbX, 4, 256, 0, 0);
                src = dst;
                dst = (dst == actA) ? actB : actA;
            }
            if (h == 0) {
                dim3 gf(nbX * nbY, 7, 2);
                if (BWv == 16)
                    conv_mfma<16, true, 91><<<gf, 256, 0, stream>>>(
                        src, wfc, cls_out_b, nullptr, cls_out, Hs, Ws, nbX, 14, 819, aoff, ATOT);
                else
                    conv_mfma<8, true, 91><<<gf, 256, 0, stream>>>(
                        src, wfc, cls_out_b, nullptr, cls_out, Hs, Ws, nbX, 14, 819, aoff, ATOT);
            } else {
                dim3 gf(nbX * nbY, 1, 2);
                if (BWv == 16)
                    conv_mfma<16, true, 4><<<gf, 256, 0, stream>>>(
                        src, wfr, reg_out_b, nullptr, reg_out, Hs, Ws, nbX, 2, 36, aoff, ATOT);
                else
                    conv_mfma<8, true, 4><<<gf, 256, 0, stream>>>(
                        src, wfr, reg_out_b, nullptr, reg_out, Hs, Ws, nbX, 2, 36, aoff, ATOT);
            }
        }
        aoff += M * 9;
    }
}